// Round 15
// baseline (378.102 us; speedup 1.0000x reference)
//
#include <hip/hip_runtime.h>
#include <stdint.h>

#define N_NODES 4096
#define NNN ((int64_t)N_NODES * (int64_t)N_NODES)
#define TOTAL4 (NNN / 4)
#define NC 12
// floor(0.9 * (N*N - 1)) = 15099493 (frac = 0.5)
#define K0_RANK 15099493u

// META layout (u32 words)
#define M_HIST1 0
#define M_HISTA 4096
#define M_HISTB 8192
#define M_DEG   8448
#define M_MXB   12544   // atomicMax of ~key over keys in bins > b1
#define M_MXS   12545   // atomicMax of ~key over keys in sub-bins > b2 (within b1)
#define M_SEL   12552   // [0]=b1 [1]=r1 [2]=b2 [3]=r2
#define M_CNTS  12800   // 1024 per-block candidate counts
#define M_WORDS 14336   // zeroed region (56 blocks x 256)

#define CHUNK_V 16384   // candidate capacity per collect block

typedef __attribute__((ext_vector_type(4))) _Float16 half4v;
typedef __attribute__((ext_vector_type(2))) _Float16 half2v;

static __device__ __forceinline__ uint32_t f2key(float f) {
    uint32_t x = __float_as_uint(f);
    return (x & 0x80000000u) ? ~x : (x | 0x80000000u);
}
static __device__ __forceinline__ float key2f(uint32_t k) {
    uint32_t x = (k & 0x80000000u) ? (k & 0x7FFFFFFFu) : ~k;
    return __uint_as_float(x);
}

// 256-thread block-wide select over nb-bin histogram -> out[0]=bin, out[1]=rank
static __device__ __forceinline__ void select_bin(const uint32_t* __restrict__ gh,
        int nb, uint32_t target, uint32_t* hl, uint32_t* sc, uint32_t* out) {
    int t = threadIdx.x;
    int per = nb >> 8;
    for (int i = t; i < nb; i += 256) hl[i] = gh[i];
    __syncthreads();
    uint32_t p = 0;
    for (int i = 0; i < per; ++i) p += hl[t * per + i];
    sc[t] = p;
    __syncthreads();
    for (int d = 1; d < 256; d <<= 1) {
        uint32_t v = (t >= d) ? sc[t - d] : 0u;
        __syncthreads();
        sc[t] += v;
        __syncthreads();
    }
    uint32_t excl = sc[t] - p;
    if (p > 0 && target >= excl && target < excl + p) {
        uint32_t cum = excl; int b = t * per;
        while (cum + hl[b] <= target) { cum += hl[b]; ++b; }
        out[0] = (uint32_t)b; out[1] = target - cum;
    }
    __syncthreads();
}

// ---------------------------------------------------------------------------
// 1) agg = sum_c w[c]*attn[c] + b ; zero META; flush LDS hist -> hist1 atomics
// ---------------------------------------------------------------------------
__global__ __launch_bounds__(256) void agg_kernel(const float* __restrict__ attn,
        const float* __restrict__ w, const float* __restrict__ bb,
        float* __restrict__ agg, uint32_t* __restrict__ meta) {
    if (blockIdx.x < 56) meta[blockIdx.x * 256 + threadIdx.x] = 0;
    __shared__ uint32_t h[4096];
    for (int i = threadIdx.x; i < 4096; i += 256) h[i] = 0;
    float wr[NC];
#pragma unroll
    for (int c = 0; c < NC; ++c) wr[c] = w[c];
    float b0 = bb[0];
    __syncthreads();
    const float4* a4 = (const float4*)attn;
    float4* o4 = (float4*)agg;
    for (int64_t i = (int64_t)blockIdx.x * 256 + threadIdx.x; i < TOTAL4; i += (int64_t)1024 * 256) {
        float ax = b0, ay = b0, az = b0, aw = b0;
#pragma unroll
        for (int c = 0; c < NC; ++c) {
            float4 t = a4[(int64_t)c * TOTAL4 + i];
            ax += wr[c] * t.x; ay += wr[c] * t.y; az += wr[c] * t.z; aw += wr[c] * t.w;
        }
        o4[i] = make_float4(ax, ay, az, aw);
        atomicAdd(&h[f2key(ax) >> 20], 1u);
        atomicAdd(&h[f2key(ay) >> 20], 1u);
        atomicAdd(&h[f2key(az) >> 20], 1u);
        atomicAdd(&h[f2key(aw) >> 20], 1u);
    }
    __syncthreads();
    for (int i = threadIdx.x; i < 4096; i += 256) {
        uint32_t c = h[i];
        if (c) atomicAdd(&meta[M_HIST1 + i], c);
    }
}

// ---------------------------------------------------------------------------
// 2) collectM: inline select1; stream agg once; emit row-major sure-bit mask M,
//    compact boundary (val, coord), fused histA, min-key-above-b1.
// ---------------------------------------------------------------------------
__global__ __launch_bounds__(256) void collectM_kernel(const float* __restrict__ agg,
        uint32_t* __restrict__ meta, uint32_t* __restrict__ M,
        float* __restrict__ candV, uint32_t* __restrict__ candC) {
    __shared__ uint32_t hl[4096];
    __shared__ uint32_t sc[256];
    __shared__ uint32_t res[2];
    __shared__ uint32_t mrow[512];
    __shared__ uint32_t cnt, ms;
    int t = threadIdx.x;
    select_bin(meta + M_HIST1, 4096, K0_RANK, hl, sc, res);
    uint32_t b1 = res[0];
    if (t == 0) {
        meta[M_SEL + 0] = res[0]; meta[M_SEL + 1] = res[1];   // same in all blocks
        cnt = 0; ms = 0xFFFFFFFFu;
    }
    for (int i = t; i < 4096; i += 256) hl[i] = 0;            // reuse as histA
    __syncthreads();
    const float4* a4 = (const float4*)agg;
    float*    regV = candV + (size_t)blockIdx.x * CHUNK_V;
    uint32_t* regC = candC + (size_t)blockIdx.x * CHUNK_V;
    int64_t base = (int64_t)blockIdx.x * 4096;     // float4 units
    int u0 = blockIdx.x * 4;
    uint32_t mn = 0xFFFFFFFFu;
    for (int it = 0; it < 16; ++it) {
        int li = it * 256 + t;                      // local float4 idx 0..4095
        float4 v = a4[base + li];
        int u = u0 + (li >> 10);
        int vcol = (li & 1023) * 4;
        float vals[4] = {v.x, v.y, v.z, v.w};
        uint32_t nib = 0;
#pragma unroll
        for (int j = 0; j < 4; ++j) {
            float val = vals[j];
            uint32_t k = f2key(val);
            uint32_t hi = k >> 20;
            if ((hi > b1) || (u == vcol + j)) nib |= (1u << j);
            if (hi > b1) mn = min(mn, k);
            else if (hi == b1) {
                uint32_t p = atomicAdd(&cnt, 1u);
                regV[p] = val;
                regC[p] = ((uint32_t)u << 12) | (uint32_t)(vcol + j);
                atomicAdd(&hl[(k >> 8) & 0xFFFu], 1u);
            }
        }
        // assemble 32-bit mask word across 8 consecutive threads (no atomics)
        uint32_t wd = nib << ((t & 7) * 4);
        wd |= (uint32_t)__shfl_xor((int)wd, 1);
        wd |= (uint32_t)__shfl_xor((int)wd, 2);
        wd |= (uint32_t)__shfl_xor((int)wd, 4);
        if ((t & 7) == 0) mrow[li >> 3] = wd;
    }
    atomicMin(&ms, mn);
    __syncthreads();
    uint32_t* Mdst = M + (size_t)blockIdx.x * 512;   // 4 rows x 128 words
    Mdst[t] = mrow[t];
    Mdst[t + 256] = mrow[t + 256];
    for (int i = t; i < 4096; i += 256) {
        uint32_t c = hl[i];
        if (c) atomicAdd(&meta[M_HISTA + i], c);
    }
    if (t == 0) {
        meta[M_CNTS + blockIdx.x] = cnt;
        if (ms != 0xFFFFFFFFu) atomicMax(&meta[M_MXB], ~ms);
    }
}

// ---------------------------------------------------------------------------
// 3) collect2 (inlined select2): histB over low byte within sub-bin b2 + mgt2
// ---------------------------------------------------------------------------
__global__ __launch_bounds__(256) void collect2_kernel(const float* __restrict__ candV,
        uint32_t* __restrict__ meta) {
    __shared__ uint32_t hl[4096];
    __shared__ uint32_t sc[256];
    __shared__ uint32_t res[2];
    __shared__ uint32_t hB[256];
    __shared__ uint32_t ms2;
    int t = threadIdx.x;
    uint32_t r1 = meta[M_SEL + 1];
    select_bin(meta + M_HISTA, 4096, r1, hl, sc, res);
    uint32_t b2 = res[0];
    hB[t] = 0;
    if (t == 0) {
        ms2 = 0xFFFFFFFFu;
        meta[M_SEL + 2] = res[0]; meta[M_SEL + 3] = res[1];   // same in all blocks
    }
    uint32_t n = meta[M_CNTS + blockIdx.x];
    const float* region = candV + (size_t)blockIdx.x * CHUNK_V;
    __syncthreads();
    uint32_t mn = 0xFFFFFFFFu;
    for (uint32_t i = t; i < n; i += 256) {
        uint32_t key = f2key(region[i]);
        uint32_t sub = (key >> 8) & 0xFFFu;
        if (sub == b2) atomicAdd(&hB[key & 0xFFu], 1u);
        else if (sub > b2) mn = min(mn, key);
    }
    atomicMin(&ms2, mn);
    __syncthreads();
    uint32_t c = hB[t];
    if (c) atomicAdd(&meta[M_HISTB + t], c);
    if (t == 0 && ms2 != 0xFFFFFFFFu) atomicMax(&meta[M_MXS], ~ms2);
}

// ---------------------------------------------------------------------------
// 4) fixupM (inlined select3): compute thresh, patch boundary cands >= thresh
// ---------------------------------------------------------------------------
__global__ __launch_bounds__(256) void fixupM_kernel(const float* __restrict__ candV,
        const uint32_t* __restrict__ candC, const uint32_t* __restrict__ meta,
        uint32_t* __restrict__ M) {
    __shared__ uint32_t h[256];
    __shared__ float thr;
    int t = threadIdx.x;
    h[t] = meta[M_HISTB + t];
    __syncthreads();
    if (t == 0) {
        uint32_t b1 = meta[M_SEL + 0], b2 = meta[M_SEL + 2], r2 = meta[M_SEL + 3];
        uint32_t cum = 0; int b = 0;
        while (cum + h[b] <= r2) { cum += h[b]; ++b; }
        uint32_t key0 = (b1 << 20) | (b2 << 8) | (uint32_t)b;
        uint32_t cle = cum + h[b];
        uint32_t key1;
        if (cle >= r2 + 2u) key1 = key0;
        else {
            int nb = b + 1;
            while (nb < 256 && h[nb] == 0) ++nb;
            if (nb < 256) key1 = (b1 << 20) | (b2 << 8) | (uint32_t)nb;
            else {
                uint32_t ks = ~meta[M_MXS];
                key1 = (ks != 0xFFFFFFFFu) ? ks : ~meta[M_MXB];
            }
        }
        float v0 = key2f(key0);
        float v1 = key2f(key1);
        thr = v0 + 0.5f * (v1 - v0);   // same formula as R1-R9 (verified)
    }
    __syncthreads();
    float th = thr;
    uint32_t n = meta[M_CNTS + blockIdx.x];
    const float*    regV = candV + (size_t)blockIdx.x * CHUNK_V;
    const uint32_t* regC = candC + (size_t)blockIdx.x * CHUNK_V;
    for (uint32_t i = t; i < n; i += 256) {
        if (regV[i] >= th) {
            uint32_t c = regC[i];
            uint32_t u = c >> 12, v = c & 0xFFFu;
            atomicOr(&M[(size_t)u * 128 + (v >> 5)], 1u << (v & 31u));
        }
    }
}

// ---------------------------------------------------------------------------
// 5) transpose bit-matrix M[u][v] -> B[v][u], accumulate deg[v]
// ---------------------------------------------------------------------------
__global__ __launch_bounds__(256) void transposeB_kernel(const uint32_t* __restrict__ M,
        uint32_t* __restrict__ B, uint32_t* __restrict__ deg) {
    __shared__ uint32_t tile[4][64][2];
    int wave = threadIdx.x >> 6, lane = threadIdx.x & 63;
    int tileId = blockIdx.x * 4 + wave;        // 4096 tiles
    int u0 = (tileId & 63) * 64;
    int v0 = (tileId >> 6) * 64;
    uint2 two = *(const uint2*)(M + (size_t)(u0 + lane) * 128 + (v0 >> 5));
    tile[wave][lane][0] = two.x;
    tile[wave][lane][1] = two.y;
    __syncthreads();
    int sh = lane & 31, hw = lane >> 5;
    uint32_t w0 = 0, w1 = 0;
#pragma unroll
    for (int i = 0; i < 32; ++i) {
        w0 |= ((tile[wave][i][hw] >> sh) & 1u) << i;
        w1 |= ((tile[wave][32 + i][hw] >> sh) & 1u) << i;
    }
    B[(size_t)(v0 + lane) * 128 + (u0 >> 5)]     = w0;
    B[(size_t)(v0 + lane) * 128 + (u0 >> 5) + 1] = w1;
    uint32_t d = __popc(w0) + __popc(w1);
    if (d) atomicAdd(&deg[v0 + lane], d);
}

// ---------------------------------------------------------------------------
// 6) gemms: fp32 compute, fp16 row-major outputs
// ---------------------------------------------------------------------------
__global__ __launch_bounds__(256) void gemm1_kernel(const float* __restrict__ x,
        const float* __restrict__ W1, const uint32_t* __restrict__ deg,
        _Float16* __restrict__ g) {
    __shared__ float xr[8 * 128];
    __shared__ float sr[8];
    int u0 = blockIdx.x * 8;
    int t = threadIdx.x;
    ((float4*)xr)[t] = ((const float4*)(x + (int64_t)u0 * 128))[t];
    if (t < 8) sr[t] = rsqrtf((float)deg[u0 + t]);
    __syncthreads();
    float acc[8] = {0, 0, 0, 0, 0, 0, 0, 0};
    for (int k = 0; k < 128; k += 4) {
        float w0 = W1[(k + 0) * 256 + t], w1 = W1[(k + 1) * 256 + t];
        float w2 = W1[(k + 2) * 256 + t], w3 = W1[(k + 3) * 256 + t];
#pragma unroll
        for (int r = 0; r < 8; ++r) {
            float4 xv = *(const float4*)&xr[r * 128 + k];
            acc[r] += xv.x * w0 + xv.y * w1 + xv.z * w2 + xv.w * w3;
        }
    }
#pragma unroll
    for (int r = 0; r < 8; ++r)
        g[(int64_t)(u0 + r) * 256 + t] = (_Float16)(sr[r] * acc[r]);
}

__global__ __launch_bounds__(256) void gemm2_kernel(const float* __restrict__ h1,
        const float* __restrict__ W2, const uint32_t* __restrict__ deg,
        _Float16* __restrict__ g2) {
    __shared__ float hr[8 * 256];
    __shared__ float sr[8];
    int u0 = blockIdx.x * 8;
    int t = threadIdx.x;
    const float4* h4 = (const float4*)(h1 + (int64_t)u0 * 256);
    ((float4*)hr)[t] = h4[t];
    ((float4*)hr)[t + 256] = h4[t + 256];
    if (t < 8) sr[t] = rsqrtf((float)deg[u0 + t]);
    __syncthreads();
    int col = t & 127;
    int roff = (t >> 7) * 4;
    float acc[4] = {0, 0, 0, 0};
    for (int k = 0; k < 256; k += 4) {
        float w0 = W2[(k + 0) * 128 + col], w1 = W2[(k + 1) * 128 + col];
        float w2 = W2[(k + 2) * 128 + col], w3 = W2[(k + 3) * 128 + col];
#pragma unroll
        for (int r = 0; r < 4; ++r) {
            float4 hv = *(const float4*)&hr[(roff + r) * 256 + k];
            acc[r] += hv.x * w0 + hv.y * w1 + hv.z * w2 + hv.w * w3;
        }
    }
#pragma unroll
    for (int r = 0; r < 4; ++r)
        g2[(int64_t)(u0 + roff + r) * 128 + col] = (_Float16)(sr[roff + r] * acc[r]);
}

// ---------------------------------------------------------------------------
// 7) spmm: decode bitmask into LDS idx list, fp16 row gathers, fp32 accum
// ---------------------------------------------------------------------------
static __device__ __forceinline__ uint32_t build_idx(const uint32_t* __restrict__ B,
                                                     int v, int t, uint16_t* idx) {
    const uint32_t* row = B + (int64_t)v * 128;
    uint32_t w0 = row[t], w1 = row[t + 64];
    uint32_t pc0 = __popc(w0), pc1 = __popc(w1);
    int s0 = (int)pc0, s1 = (int)pc1;
#pragma unroll
    for (int d = 1; d < 64; d <<= 1) {
        int a = __shfl_up(s0, d);
        int b = __shfl_up(s1, d);
        if (t >= d) { s0 += a; s1 += b; }
    }
    uint32_t tot0 = (uint32_t)__shfl(s0, 63);
    uint32_t cnt  = tot0 + (uint32_t)__shfl(s1, 63);
    uint32_t p = (uint32_t)s0 - pc0;
    uint32_t m = w0;
    int ub = t * 32;
    while (m) { int bi = __ffs(m) - 1; m &= m - 1; idx[p++] = (uint16_t)(ub + bi); }
    p = tot0 + (uint32_t)s1 - pc1;
    m = w1;
    ub = (t + 64) * 32;
    while (m) { int bi = __ffs(m) - 1; m &= m - 1; idx[p++] = (uint16_t)(ub + bi); }
    __syncthreads();
    return cnt;
}

__global__ __launch_bounds__(64) void spmm1_kernel(const uint32_t* __restrict__ B,
        const _Float16* __restrict__ g, const uint32_t* __restrict__ deg,
        const float* __restrict__ b1, float* __restrict__ h1) {
    __shared__ uint16_t idx[4096];
    int v = blockIdx.x;
    int t = threadIdx.x;
    uint32_t cnt = build_idx(B, v, t, idx);
    const half4v* g4 = (const half4v*)g;
    float4 acc = make_float4(0.f, 0.f, 0.f, 0.f);
    uint32_t i = 0;
    for (; i + 8 <= cnt; i += 8) {
#pragma unroll
        for (int q = 0; q < 8; ++q) {
            half4v a = g4[idx[i + q] * 64 + t];
            acc.x += (float)a[0]; acc.y += (float)a[1];
            acc.z += (float)a[2]; acc.w += (float)a[3];
        }
    }
    for (; i < cnt; ++i) {
        half4v a = g4[idx[i] * 64 + t];
        acc.x += (float)a[0]; acc.y += (float)a[1];
        acc.z += (float)a[2]; acc.w += (float)a[3];
    }
    float sv = rsqrtf((float)deg[v]);
    float4 bb = ((const float4*)b1)[t];
    float4 r;
    r.x = fmaxf(sv * acc.x + bb.x, 0.f);
    r.y = fmaxf(sv * acc.y + bb.y, 0.f);
    r.z = fmaxf(sv * acc.z + bb.z, 0.f);
    r.w = fmaxf(sv * acc.w + bb.w, 0.f);
    ((float4*)h1)[(int64_t)v * 64 + t] = r;
}

__global__ __launch_bounds__(64) void spmm2_kernel(const uint32_t* __restrict__ B,
        const _Float16* __restrict__ g2, const uint32_t* __restrict__ deg,
        const float* __restrict__ b2, float* __restrict__ out) {
    __shared__ uint16_t idx[4096];
    int v = blockIdx.x;
    int t = threadIdx.x;
    uint32_t cnt = build_idx(B, v, t, idx);
    const half2v* gp = (const half2v*)g2;
    float ax = 0.f, ay = 0.f;
    uint32_t i = 0;
    for (; i + 8 <= cnt; i += 8) {
#pragma unroll
        for (int q = 0; q < 8; ++q) {
            half2v a = gp[idx[i + q] * 64 + t];
            ax += (float)a[0]; ay += (float)a[1];
        }
    }
    for (; i < cnt; ++i) {
        half2v a = gp[idx[i] * 64 + t];
        ax += (float)a[0]; ay += (float)a[1];
    }
    float sv = rsqrtf((float)deg[v]);
    float2 bb = ((const float2*)b2)[t];
    float2 r;
    r.x = sv * ax + bb.x;
    r.y = sv * ay + bb.y;
    ((float2*)out)[(int64_t)v * 64 + t] = r;
}

// ---------------------------------------------------------------------------
extern "C" void kernel_launch(void* const* d_in, const int* in_sizes, int n_in,
                              void* d_out, int out_size, void* d_ws, size_t ws_size,
                              hipStream_t stream) {
    const float* x    = (const float*)d_in[0];
    const float* attn = (const float*)d_in[1];
    const float* aggw = (const float*)d_in[2];
    const float* aggb = (const float*)d_in[3];
    const float* W1   = (const float*)d_in[4];
    const float* b1   = (const float*)d_in[5];
    const float* W2   = (const float*)d_in[6];
    const float* b2   = (const float*)d_in[7];
    float* out = (float*)d_out;

    char* ws = (char*)d_ws;
    size_t OFF_AGG   = 0;
    size_t OFF_META  = OFF_AGG + (size_t)NNN * 4;                   // 56 KB zeroed
    size_t OFF_M     = OFF_META + 65536;                            // 2 MB rowmask
    size_t OFF_B     = OFF_M + (size_t)N_NODES * 128 * 4;           // 2 MB
    size_t OFF_CV    = OFF_B + (size_t)N_NODES * 128 * 4;           // 64 MB
    size_t OFF_CC    = OFF_CV + (size_t)1024 * CHUNK_V * 4;         // 64 MB
    size_t OFF_G     = OFF_CC + (size_t)1024 * CHUNK_V * 4;         // 2 MB fp16
    size_t OFF_H1    = OFF_G + (size_t)N_NODES * 256 * 2;           // 4 MB
    size_t OFF_G2    = OFF_H1 + (size_t)N_NODES * 256 * 4;          // 1 MB fp16

    float*    agg   = (float*)(ws + OFF_AGG);
    uint32_t* meta  = (uint32_t*)(ws + OFF_META);
    uint32_t* Mm    = (uint32_t*)(ws + OFF_M);
    uint32_t* Bm    = (uint32_t*)(ws + OFF_B);
    float*    candV = (float*)(ws + OFF_CV);
    uint32_t* candC = (uint32_t*)(ws + OFF_CC);
    _Float16* g     = (_Float16*)(ws + OFF_G);
    float*    h1    = (float*)(ws + OFF_H1);
    _Float16* g2    = (_Float16*)(ws + OFF_G2);
    uint32_t* deg   = meta + M_DEG;

    agg_kernel<<<1024, 256, 0, stream>>>(attn, aggw, aggb, agg, meta);
    collectM_kernel<<<1024, 256, 0, stream>>>(agg, meta, Mm, candV, candC);
    collect2_kernel<<<1024, 256, 0, stream>>>(candV, meta);
    fixupM_kernel<<<1024, 256, 0, stream>>>(candV, candC, meta, Mm);
    transposeB_kernel<<<1024, 256, 0, stream>>>(Mm, Bm, deg);

    gemm1_kernel<<<512, 256, 0, stream>>>(x, W1, deg, g);
    spmm1_kernel<<<N_NODES, 64, 0, stream>>>(Bm, g, deg, b1, h1);
    gemm2_kernel<<<512, 256, 0, stream>>>(h1, W2, deg, g2);
    spmm2_kernel<<<N_NODES, 64, 0, stream>>>(Bm, g2, deg, b2, out);
}

// Round 16
// 366.398 us; speedup vs baseline: 1.0319x; 1.0319x over previous
//
#include <hip/hip_runtime.h>
#include <stdint.h>

#define N_NODES 4096
#define NNN ((int64_t)N_NODES * (int64_t)N_NODES)
#define TOTAL4 (NNN / 4)
#define NC 12
// floor(0.9 * (N*N - 1)) = 15099493 (frac = 0.5)
#define K0_RANK 15099493u

// sample: rows u = 25*r, r in [0,164) -> N_s = 164*4096 = 671744
#define SROWS 164
#define SSTRIDE 25
#define LO_RANK 601210u   // floor(0.895 * NSAMP)
#define HI_RANK 607929u   // ceil (0.905 * NSAMP)

// META layout (u32 words)
#define M_SHIST 0        // 4096  sample hist (key>>20)
#define M_CH1   4096     // 256   candidate top-bin hist (rel blo, clamped)
#define M_CH2   4352     // 4096  candidate mid-12 hist within b1c
#define M_HB    8448     // 256   candidate low-8 hist within prefix24
#define M_DEG   8704     // 4096
#define M_CNTS  12800    // 1024  per-block candidate counts
#define M_BLO   13824
#define M_BHI   13825
#define M_NBEL  13826
#define M_MXM   13827    // atomicMax of ~key over cand keys with (key>>8) > prefix24
#define M_SELX  13828    // [0]=b1c [1]=r1 [2]=b2c [3]=r2 [4]=thresh bits
#define M_WORDS 14336

#define CHUNK_V 16384

typedef __attribute__((ext_vector_type(4))) _Float16 half4v;
typedef __attribute__((ext_vector_type(2))) _Float16 half2v;

static __device__ __forceinline__ uint32_t f2key(float f) {
    uint32_t x = __float_as_uint(f);
    return (x & 0x80000000u) ? ~x : (x | 0x80000000u);
}
static __device__ __forceinline__ float key2f(uint32_t k) {
    uint32_t x = (k & 0x80000000u) ? (k & 0x7FFFFFFFu) : ~k;
    return __uint_as_float(x);
}

// 256-thread block-wide select over nb-bin hist -> out[0]=bin, out[1]=residual rank
static __device__ __forceinline__ void select_bin(const uint32_t* __restrict__ gh,
        int nb, uint32_t target, uint32_t* hl, uint32_t* sc, uint32_t* out) {
    int t = threadIdx.x;
    int per = nb >> 8;
    for (int i = t; i < nb; i += 256) hl[i] = gh[i];
    __syncthreads();
    uint32_t p = 0;
    for (int i = 0; i < per; ++i) p += hl[t * per + i];
    sc[t] = p;
    __syncthreads();
    for (int d = 1; d < 256; d <<= 1) {
        uint32_t v = (t >= d) ? sc[t - d] : 0u;
        __syncthreads();
        sc[t] += v;
        __syncthreads();
    }
    uint32_t excl = sc[t] - p;
    if (p > 0 && target >= excl && target < excl + p) {
        uint32_t cum = excl; int b = t * per;
        while (cum + hl[b] <= target) { cum += hl[b]; ++b; }
        out[0] = (uint32_t)b; out[1] = target - cum;
    }
    __syncthreads();
}

// ---------------------------------------------------------------------------
// S) sample 164 rows -> hist of key>>20.  META zeroed by memset BEFORE this
//    kernel (race-free: stream-ordered).
// ---------------------------------------------------------------------------
__global__ __launch_bounds__(256) void sample_kernel(const float* __restrict__ attn,
        const float* __restrict__ w, const float* __restrict__ bb,
        uint32_t* __restrict__ meta) {
    __shared__ uint32_t h[4096];
    for (int i = threadIdx.x; i < 4096; i += 256) h[i] = 0;
    float wr[NC];
#pragma unroll
    for (int c = 0; c < NC; ++c) wr[c] = w[c];
    float b0 = bb[0];
    __syncthreads();
    const float4* a4 = (const float4*)attn;
    for (int idx = blockIdx.x * 256 + threadIdx.x; idx < SROWS * 1024; idx += 256 * 256) {
        int r = idx >> 10;
        int64_t off = (int64_t)(r * SSTRIDE) * 1024 + (idx & 1023);
        float ax = b0, ay = b0, az = b0, aw = b0;
#pragma unroll
        for (int c = 0; c < NC; ++c) {
            float4 t = a4[(int64_t)c * TOTAL4 + off];
            ax += wr[c] * t.x; ay += wr[c] * t.y; az += wr[c] * t.z; aw += wr[c] * t.w;
        }
        atomicAdd(&h[f2key(ax) >> 20], 1u);
        atomicAdd(&h[f2key(ay) >> 20], 1u);
        atomicAdd(&h[f2key(az) >> 20], 1u);
        atomicAdd(&h[f2key(aw) >> 20], 1u);
    }
    __syncthreads();
    for (int i = threadIdx.x; i < 4096; i += 256) {
        uint32_t c = h[i];
        if (c) atomicAdd(&meta[M_SHIST + i], c);
    }
}

// S2) bracket: blo = bin of sample rank LO, bhi = bin of sample rank HI
__global__ __launch_bounds__(256) void bracket_kernel(uint32_t* __restrict__ meta) {
    __shared__ uint32_t hl[4096];
    __shared__ uint32_t sc[256];
    __shared__ uint32_t res[2];
    select_bin(meta + M_SHIST, 4096, LO_RANK, hl, sc, res);
    if (threadIdx.x == 0) meta[M_BLO] = res[0];
    __syncthreads();
    select_bin(meta + M_SHIST, 4096, HI_RANK, hl, sc, res);
    if (threadIdx.x == 0) meta[M_BHI] = res[0];
}

// ---------------------------------------------------------------------------
// A) fused agg+mask+collect: NO agg store.
// ---------------------------------------------------------------------------
__global__ __launch_bounds__(256) void aggmask_kernel(const float* __restrict__ attn,
        const float* __restrict__ w, const float* __restrict__ bb,
        uint32_t* __restrict__ meta, uint32_t* __restrict__ M,
        float* __restrict__ candV, uint32_t* __restrict__ candC) {
    __shared__ uint32_t mrow[512];
    __shared__ uint32_t candH[256];
    __shared__ uint32_t cnt, nbel;
    int t = threadIdx.x;
    for (int i = t; i < 256; i += 256) candH[i] = 0;
    if (t == 0) { cnt = 0; nbel = 0; }
    float wr[NC];
#pragma unroll
    for (int c = 0; c < NC; ++c) wr[c] = w[c];
    float b0 = bb[0];
    uint32_t blo = meta[M_BLO], bhi = meta[M_BHI];
    __syncthreads();
    const float4* a4 = (const float4*)attn;
    float*    regV = candV + (size_t)blockIdx.x * CHUNK_V;
    uint32_t* regC = candC + (size_t)blockIdx.x * CHUNK_V;
    int64_t base = (int64_t)blockIdx.x * 4096;
    int u0 = blockIdx.x * 4;
    uint32_t below_t = 0;
    for (int it = 0; it < 16; ++it) {
        int li = it * 256 + t;
        float ax = b0, ay = b0, az = b0, aw = b0;
#pragma unroll
        for (int c = 0; c < NC; ++c) {
            float4 v = a4[(int64_t)c * TOTAL4 + base + li];
            ax += wr[c] * v.x; ay += wr[c] * v.y; az += wr[c] * v.z; aw += wr[c] * v.w;
        }
        int u = u0 + (li >> 10);
        int vcol = (li & 1023) * 4;
        float vals[4] = {ax, ay, az, aw};
        uint32_t nib = 0;
#pragma unroll
        for (int j = 0; j < 4; ++j) {
            float val = vals[j];
            uint32_t k = f2key(val);
            uint32_t top = k >> 20;
            if ((top > bhi) || (u == vcol + j)) nib |= (1u << j);
            if (top < blo) ++below_t;
            else if (top <= bhi) {
                uint32_t p = atomicAdd(&cnt, 1u);
                regV[p] = val;
                regC[p] = ((uint32_t)u << 12) | (uint32_t)(vcol + j);
                atomicAdd(&candH[min(top - blo, 255u)], 1u);
            }
        }
        uint32_t wd = nib << ((t & 7) * 4);
        wd |= (uint32_t)__shfl_xor((int)wd, 1);
        wd |= (uint32_t)__shfl_xor((int)wd, 2);
        wd |= (uint32_t)__shfl_xor((int)wd, 4);
        if ((t & 7) == 0) mrow[li >> 3] = wd;
    }
    atomicAdd(&nbel, below_t);
    __syncthreads();
    uint32_t* Mdst = M + (size_t)blockIdx.x * 512;
    Mdst[t] = mrow[t];
    Mdst[t + 256] = mrow[t + 256];
    uint32_t c = candH[t];
    if (c) atomicAdd(&meta[M_CH1 + t], c);
    if (t == 0) {
        meta[M_CNTS + blockIdx.x] = cnt;
        if (nbel) atomicAdd(&meta[M_NBEL], nbel);
    }
}

// ---------------------------------------------------------------------------
// C2) select level-1 over candHist1 (target r = K0 - nBelow); hist mid-12 bits
// ---------------------------------------------------------------------------
__global__ __launch_bounds__(256) void cand1_kernel(const float* __restrict__ candV,
        uint32_t* __restrict__ meta) {
    __shared__ uint32_t hl[4096];
    __shared__ uint32_t sc[256];
    __shared__ uint32_t res[2];
    int t = threadIdx.x;
    uint32_t r = K0_RANK - meta[M_NBEL];
    uint32_t blo = meta[M_BLO];
    select_bin(meta + M_CH1, 256, r, hl, sc, res);
    uint32_t b1c = blo + res[0];
    uint32_t r1 = res[1];
    if (t == 0) { meta[M_SELX + 0] = b1c; meta[M_SELX + 1] = r1; }
    for (int i = t; i < 4096; i += 256) hl[i] = 0;
    __syncthreads();
    uint32_t n = meta[M_CNTS + blockIdx.x];
    const float* region = candV + (size_t)blockIdx.x * CHUNK_V;
    for (uint32_t i = t; i < n; i += 256) {
        uint32_t key = f2key(region[i]);
        if ((key >> 20) == b1c) atomicAdd(&hl[(key >> 8) & 0xFFFu], 1u);
    }
    __syncthreads();
    for (int i = t; i < 4096; i += 256) {
        uint32_t c = hl[i];
        if (c) atomicAdd(&meta[M_CH2 + i], c);
    }
}

// ---------------------------------------------------------------------------
// C3) select level-2 over candHist2; hist low-8 within prefix24 + min above
// ---------------------------------------------------------------------------
__global__ __launch_bounds__(256) void cand2_kernel(const float* __restrict__ candV,
        uint32_t* __restrict__ meta) {
    __shared__ uint32_t hl[4096];
    __shared__ uint32_t sc[256];
    __shared__ uint32_t res[2];
    __shared__ uint32_t hB[256];
    __shared__ uint32_t ms;
    int t = threadIdx.x;
    uint32_t r1 = meta[M_SELX + 1];
    uint32_t b1c = meta[M_SELX + 0];
    select_bin(meta + M_CH2, 4096, r1, hl, sc, res);
    uint32_t p24 = (b1c << 12) | res[0];
    hB[t] = 0;
    if (t == 0) {
        ms = 0xFFFFFFFFu;
        meta[M_SELX + 2] = res[0]; meta[M_SELX + 3] = res[1];
    }
    uint32_t n = meta[M_CNTS + blockIdx.x];
    const float* region = candV + (size_t)blockIdx.x * CHUNK_V;
    __syncthreads();
    uint32_t mn = 0xFFFFFFFFu;
    for (uint32_t i = t; i < n; i += 256) {
        uint32_t key = f2key(region[i]);
        uint32_t hi = key >> 8;
        if (hi == p24) atomicAdd(&hB[key & 0xFFu], 1u);
        else if (hi > p24) mn = min(mn, key);
    }
    atomicMin(&ms, mn);
    __syncthreads();
    uint32_t c = hB[t];
    if (c) atomicAdd(&meta[M_HB + t], c);
    if (t == 0 && ms != 0xFFFFFFFFu) atomicMax(&meta[M_MXM], ~ms);
}

// ---------------------------------------------------------------------------
// C4) walk histB -> key0, thresh; patch candidates >= thresh into M
// ---------------------------------------------------------------------------
__global__ __launch_bounds__(256) void candfix_kernel(const float* __restrict__ candV,
        const uint32_t* __restrict__ candC, uint32_t* __restrict__ meta,
        uint32_t* __restrict__ M) {
    __shared__ uint32_t h[256];
    __shared__ float thr;
    int t = threadIdx.x;
    h[t] = meta[M_HB + t];
    __syncthreads();
    if (t == 0) {
        uint32_t b1c = meta[M_SELX + 0], b2c = meta[M_SELX + 2], r2 = meta[M_SELX + 3];
        uint32_t cum = 0; int b = 0;
        while (b < 255 && cum + h[b] <= r2) { cum += h[b]; ++b; }   // bounded (equiv for valid data)
        uint32_t key0 = (b1c << 20) | (b2c << 8) | (uint32_t)b;
        uint32_t cle = cum + h[b];
        uint32_t key1;
        if (cle >= r2 + 2u) key1 = key0;
        else {
            int nb = b + 1;
            while (nb < 256 && h[nb] == 0) ++nb;
            key1 = (nb < 256) ? ((b1c << 20) | (b2c << 8) | (uint32_t)nb) : ~meta[M_MXM];
        }
        float v0 = key2f(key0);
        float v1 = key2f(key1);
        thr = v0 + 0.5f * (v1 - v0);   // same formula as R1-R15 (verified)
        meta[M_SELX + 4] = __float_as_uint(thr);
    }
    __syncthreads();
    float th = thr;
    uint32_t n = meta[M_CNTS + blockIdx.x];
    const float*    regV = candV + (size_t)blockIdx.x * CHUNK_V;
    const uint32_t* regC = candC + (size_t)blockIdx.x * CHUNK_V;
    for (uint32_t i = t; i < n; i += 256) {
        if (regV[i] >= th) {
            uint32_t c = regC[i];
            uint32_t u = c >> 12, v = c & 0xFFFu;
            atomicOr(&M[(size_t)u * 128 + (v >> 5)], 1u << (v & 31u));
        }
    }
}

// ---------------------------------------------------------------------------
// T) transpose M[u][v] -> B[v][u], deg[v]
// ---------------------------------------------------------------------------
__global__ __launch_bounds__(256) void transposeB_kernel(const uint32_t* __restrict__ M,
        uint32_t* __restrict__ B, uint32_t* __restrict__ deg) {
    __shared__ uint32_t tile[4][64][2];
    int wave = threadIdx.x >> 6, lane = threadIdx.x & 63;
    int tileId = blockIdx.x * 4 + wave;
    int u0 = (tileId & 63) * 64;
    int v0 = (tileId >> 6) * 64;
    uint2 two = *(const uint2*)(M + (size_t)(u0 + lane) * 128 + (v0 >> 5));
    tile[wave][lane][0] = two.x;
    tile[wave][lane][1] = two.y;
    __syncthreads();
    int sh = lane & 31, hw = lane >> 5;
    uint32_t w0 = 0, w1 = 0;
#pragma unroll
    for (int i = 0; i < 32; ++i) {
        w0 |= ((tile[wave][i][hw] >> sh) & 1u) << i;
        w1 |= ((tile[wave][32 + i][hw] >> sh) & 1u) << i;
    }
    B[(size_t)(v0 + lane) * 128 + (u0 >> 5)]     = w0;
    B[(size_t)(v0 + lane) * 128 + (u0 >> 5) + 1] = w1;
    uint32_t d = __popc(w0) + __popc(w1);
    if (d) atomicAdd(&deg[v0 + lane], d);
}

// ---------------------------------------------------------------------------
// gemms: fp32 compute, fp16 row-major outputs (R15, verified)
// ---------------------------------------------------------------------------
__global__ __launch_bounds__(256) void gemm1_kernel(const float* __restrict__ x,
        const float* __restrict__ W1, const uint32_t* __restrict__ deg,
        _Float16* __restrict__ g) {
    __shared__ float xr[8 * 128];
    __shared__ float sr[8];
    int u0 = blockIdx.x * 8;
    int t = threadIdx.x;
    ((float4*)xr)[t] = ((const float4*)(x + (int64_t)u0 * 128))[t];
    if (t < 8) sr[t] = rsqrtf((float)deg[u0 + t]);
    __syncthreads();
    float acc[8] = {0, 0, 0, 0, 0, 0, 0, 0};
    for (int k = 0; k < 128; k += 4) {
        float w0 = W1[(k + 0) * 256 + t], w1 = W1[(k + 1) * 256 + t];
        float w2 = W1[(k + 2) * 256 + t], w3 = W1[(k + 3) * 256 + t];
#pragma unroll
        for (int r = 0; r < 8; ++r) {
            float4 xv = *(const float4*)&xr[r * 128 + k];
            acc[r] += xv.x * w0 + xv.y * w1 + xv.z * w2 + xv.w * w3;
        }
    }
#pragma unroll
    for (int r = 0; r < 8; ++r)
        g[(int64_t)(u0 + r) * 256 + t] = (_Float16)(sr[r] * acc[r]);
}

__global__ __launch_bounds__(256) void gemm2_kernel(const float* __restrict__ h1,
        const float* __restrict__ W2, const uint32_t* __restrict__ deg,
        _Float16* __restrict__ g2) {
    __shared__ float hr[8 * 256];
    __shared__ float sr[8];
    int u0 = blockIdx.x * 8;
    int t = threadIdx.x;
    const float4* h4 = (const float4*)(h1 + (int64_t)u0 * 256);
    ((float4*)hr)[t] = h4[t];
    ((float4*)hr)[t + 256] = h4[t + 256];
    if (t < 8) sr[t] = rsqrtf((float)deg[u0 + t]);
    __syncthreads();
    int col = t & 127;
    int roff = (t >> 7) * 4;
    float acc[4] = {0, 0, 0, 0};
    for (int k = 0; k < 256; k += 4) {
        float w0 = W2[(k + 0) * 128 + col], w1 = W2[(k + 1) * 128 + col];
        float w2 = W2[(k + 2) * 128 + col], w3 = W2[(k + 3) * 128 + col];
#pragma unroll
        for (int r = 0; r < 4; ++r) {
            float4 hv = *(const float4*)&hr[(roff + r) * 256 + k];
            acc[r] += hv.x * w0 + hv.y * w1 + hv.z * w2 + hv.w * w3;
        }
    }
#pragma unroll
    for (int r = 0; r < 4; ++r)
        g2[(int64_t)(u0 + roff + r) * 128 + col] = (_Float16)(sr[roff + r] * acc[r]);
}

// ---------------------------------------------------------------------------
// spmm: decode bitmask into LDS idx list, fp16 row gathers, fp32 accum (R15)
// ---------------------------------------------------------------------------
static __device__ __forceinline__ uint32_t build_idx(const uint32_t* __restrict__ B,
                                                     int v, int t, uint16_t* idx) {
    const uint32_t* row = B + (int64_t)v * 128;
    uint32_t w0 = row[t], w1 = row[t + 64];
    uint32_t pc0 = __popc(w0), pc1 = __popc(w1);
    int s0 = (int)pc0, s1 = (int)pc1;
#pragma unroll
    for (int d = 1; d < 64; d <<= 1) {
        int a = __shfl_up(s0, d);
        int b = __shfl_up(s1, d);
        if (t >= d) { s0 += a; s1 += b; }
    }
    uint32_t tot0 = (uint32_t)__shfl(s0, 63);
    uint32_t cnt  = tot0 + (uint32_t)__shfl(s1, 63);
    uint32_t p = (uint32_t)s0 - pc0;
    uint32_t m = w0;
    int ub = t * 32;
    while (m) { int bi = __ffs(m) - 1; m &= m - 1; idx[p++] = (uint16_t)(ub + bi); }
    p = tot0 + (uint32_t)s1 - pc1;
    m = w1;
    ub = (t + 64) * 32;
    while (m) { int bi = __ffs(m) - 1; m &= m - 1; idx[p++] = (uint16_t)(ub + bi); }
    __syncthreads();
    return cnt;
}

__global__ __launch_bounds__(64) void spmm1_kernel(const uint32_t* __restrict__ B,
        const _Float16* __restrict__ g, const uint32_t* __restrict__ deg,
        const float* __restrict__ b1, float* __restrict__ h1) {
    __shared__ uint16_t idx[4096];
    int v = blockIdx.x;
    int t = threadIdx.x;
    uint32_t cnt = build_idx(B, v, t, idx);
    const half4v* g4 = (const half4v*)g;
    float4 acc = make_float4(0.f, 0.f, 0.f, 0.f);
    uint32_t i = 0;
    for (; i + 8 <= cnt; i += 8) {
#pragma unroll
        for (int q = 0; q < 8; ++q) {
            half4v a = g4[idx[i + q] * 64 + t];
            acc.x += (float)a[0]; acc.y += (float)a[1];
            acc.z += (float)a[2]; acc.w += (float)a[3];
        }
    }
    for (; i < cnt; ++i) {
        half4v a = g4[idx[i] * 64 + t];
        acc.x += (float)a[0]; acc.y += (float)a[1];
        acc.z += (float)a[2]; acc.w += (float)a[3];
    }
    float sv = rsqrtf((float)deg[v]);
    float4 bb = ((const float4*)b1)[t];
    float4 r;
    r.x = fmaxf(sv * acc.x + bb.x, 0.f);
    r.y = fmaxf(sv * acc.y + bb.y, 0.f);
    r.z = fmaxf(sv * acc.z + bb.z, 0.f);
    r.w = fmaxf(sv * acc.w + bb.w, 0.f);
    ((float4*)h1)[(int64_t)v * 64 + t] = r;
}

__global__ __launch_bounds__(64) void spmm2_kernel(const uint32_t* __restrict__ B,
        const _Float16* __restrict__ g2, const uint32_t* __restrict__ deg,
        const float* __restrict__ b2, float* __restrict__ out) {
    __shared__ uint16_t idx[4096];
    int v = blockIdx.x;
    int t = threadIdx.x;
    uint32_t cnt = build_idx(B, v, t, idx);
    const half2v* gp = (const half2v*)g2;
    float ax = 0.f, ay = 0.f;
    uint32_t i = 0;
    for (; i + 8 <= cnt; i += 8) {
#pragma unroll
        for (int q = 0; q < 8; ++q) {
            half2v a = gp[idx[i + q] * 64 + t];
            ax += (float)a[0]; ay += (float)a[1];
        }
    }
    for (; i < cnt; ++i) {
        half2v a = gp[idx[i] * 64 + t];
        ax += (float)a[0]; ay += (float)a[1];
    }
    float sv = rsqrtf((float)deg[v]);
    float2 bb = ((const float2*)b2)[t];
    float2 r;
    r.x = sv * ax + bb.x;
    r.y = sv * ay + bb.y;
    ((float2*)out)[(int64_t)v * 64 + t] = r;
}

// ---------------------------------------------------------------------------
extern "C" void kernel_launch(void* const* d_in, const int* in_sizes, int n_in,
                              void* d_out, int out_size, void* d_ws, size_t ws_size,
                              hipStream_t stream) {
    const float* x    = (const float*)d_in[0];
    const float* attn = (const float*)d_in[1];
    const float* aggw = (const float*)d_in[2];
    const float* aggb = (const float*)d_in[3];
    const float* W1   = (const float*)d_in[4];
    const float* b1   = (const float*)d_in[5];
    const float* W2   = (const float*)d_in[6];
    const float* b2   = (const float*)d_in[7];
    float* out = (float*)d_out;

    char* ws = (char*)d_ws;
    size_t OFF_META  = 0;                                           // 56 KB
    size_t OFF_M     = OFF_META + 65536;                            // 2 MB rowmask
    size_t OFF_B     = OFF_M + (size_t)N_NODES * 128 * 4;           // 2 MB
    size_t OFF_CV    = OFF_B + (size_t)N_NODES * 128 * 4;           // 64 MB
    size_t OFF_CC    = OFF_CV + (size_t)1024 * CHUNK_V * 4;         // 64 MB
    size_t OFF_G     = OFF_CC + (size_t)1024 * CHUNK_V * 4;         // 2 MB fp16
    size_t OFF_H1    = OFF_G + (size_t)N_NODES * 256 * 2;           // 4 MB
    size_t OFF_G2    = OFF_H1 + (size_t)N_NODES * 256 * 4;          // 1 MB fp16

    uint32_t* meta  = (uint32_t*)(ws + OFF_META);
    uint32_t* Mm    = (uint32_t*)(ws + OFF_M);
    uint32_t* Bm    = (uint32_t*)(ws + OFF_B);
    float*    candV = (float*)(ws + OFF_CV);
    uint32_t* candC = (uint32_t*)(ws + OFF_CC);
    _Float16* g     = (_Float16*)(ws + OFF_G);
    float*    h1    = (float*)(ws + OFF_H1);
    _Float16* g2    = (_Float16*)(ws + OFF_G2);
    uint32_t* deg   = meta + M_DEG;

    // race-free META zeroing: stream-ordered, completes before sample_kernel
    hipMemsetAsync(meta, 0, (size_t)M_WORDS * 4, stream);

    sample_kernel<<<256, 256, 0, stream>>>(attn, aggw, aggb, meta);
    bracket_kernel<<<1, 256, 0, stream>>>(meta);
    aggmask_kernel<<<1024, 256, 0, stream>>>(attn, aggw, aggb, meta, Mm, candV, candC);
    cand1_kernel<<<1024, 256, 0, stream>>>(candV, meta);
    cand2_kernel<<<1024, 256, 0, stream>>>(candV, meta);
    candfix_kernel<<<1024, 256, 0, stream>>>(candV, candC, meta, Mm);
    transposeB_kernel<<<1024, 256, 0, stream>>>(Mm, Bm, deg);

    gemm1_kernel<<<512, 256, 0, stream>>>(x, W1, deg, g);
    spmm1_kernel<<<N_NODES, 64, 0, stream>>>(Bm, g, deg, b1, h1);
    gemm2_kernel<<<512, 256, 0, stream>>>(h1, W2, deg, g2);
    spmm2_kernel<<<N_NODES, 64, 0, stream>>>(Bm, g2, deg, b2, out);
}

// Round 17
// 350.327 us; speedup vs baseline: 1.0793x; 1.0459x over previous
//
#include <hip/hip_runtime.h>
#include <stdint.h>

#define N_NODES 4096
#define NNN ((int64_t)N_NODES * (int64_t)N_NODES)
#define TOTAL4 (NNN / 4)
#define NC 12
// floor(0.9 * (N*N - 1)) = 15099493 (frac = 0.5)
#define K0_RANK 15099493u

// sample: rows u = 25*r, r in [0,164) -> N_s = 164*4096 = 671744
#define SROWS 164
#define SSTRIDE 25
#define LO_RANK 601210u   // floor(0.895 * NSAMP)
#define HI_RANK 607929u   // ceil (0.905 * NSAMP)

// META layout (u32 words)
#define M_SHIST 0        // 4096  sample hist (key>>20)
#define M_CH1   4096     // 256   candidate top-bin hist (rel blo, clamped)
#define M_CH2   4352     // 4096  candidate mid-12 hist within b1c
#define M_HB    8448     // 256   candidate low-8 hist within prefix24
#define M_DEG   8704     // 4096
#define M_CNTS  12800    // 1024  per-block candidate counts
#define M_BLO   13824
#define M_BHI   13825
#define M_NBEL  13826
#define M_MXM   13827    // atomicMax of ~key over cand keys with (key>>8) > prefix24
#define M_SELX  13828    // [0]=b1c [1]=r1 [2]=b2c [3]=r2 [4]=thresh bits
#define M_WORDS 14336

#define CHUNK_V 16384

typedef __attribute__((ext_vector_type(2))) _Float16 half2v;

static __device__ __forceinline__ uint32_t f2key(float f) {
    uint32_t x = __float_as_uint(f);
    return (x & 0x80000000u) ? ~x : (x | 0x80000000u);
}
static __device__ __forceinline__ float key2f(uint32_t k) {
    uint32_t x = (k & 0x80000000u) ? (k & 0x7FFFFFFFu) : ~k;
    return __uint_as_float(x);
}

// 256-thread block-wide select over nb-bin hist -> out[0]=bin, out[1]=residual rank
static __device__ __forceinline__ void select_bin(const uint32_t* __restrict__ gh,
        int nb, uint32_t target, uint32_t* hl, uint32_t* sc, uint32_t* out) {
    int t = threadIdx.x;
    int per = nb >> 8;
    for (int i = t; i < nb; i += 256) hl[i] = gh[i];
    __syncthreads();
    uint32_t p = 0;
    for (int i = 0; i < per; ++i) p += hl[t * per + i];
    sc[t] = p;
    __syncthreads();
    for (int d = 1; d < 256; d <<= 1) {
        uint32_t v = (t >= d) ? sc[t - d] : 0u;
        __syncthreads();
        sc[t] += v;
        __syncthreads();
    }
    uint32_t excl = sc[t] - p;
    if (p > 0 && target >= excl && target < excl + p) {
        uint32_t cum = excl; int b = t * per;
        while (cum + hl[b] <= target) { cum += hl[b]; ++b; }
        out[0] = (uint32_t)b; out[1] = target - cum;
    }
    __syncthreads();
}

// ---------------------------------------------------------------------------
// S) sample 164 rows -> hist of key>>20; convert x -> fp16.
//    META zeroed by stream-ordered memset BEFORE this kernel (race-free).
// ---------------------------------------------------------------------------
__global__ __launch_bounds__(256) void sample_kernel(const float* __restrict__ attn,
        const float* __restrict__ w, const float* __restrict__ bb,
        uint32_t* __restrict__ meta, const float* __restrict__ x,
        _Float16* __restrict__ x_h) {
    // x -> fp16 (4096*128 = 524288 floats = 262144 float2)
    {
        const float2* x2 = (const float2*)x;
        half2v* xh2 = (half2v*)x_h;
        for (int i = blockIdx.x * 256 + threadIdx.x; i < 262144; i += 256 * 256) {
            float2 v = x2[i];
            half2v h; h[0] = (_Float16)v.x; h[1] = (_Float16)v.y;
            xh2[i] = h;
        }
    }
    __shared__ uint32_t h[4096];
    for (int i = threadIdx.x; i < 4096; i += 256) h[i] = 0;
    float wr[NC];
#pragma unroll
    for (int c = 0; c < NC; ++c) wr[c] = w[c];
    float b0 = bb[0];
    __syncthreads();
    const float4* a4 = (const float4*)attn;
    for (int idx = blockIdx.x * 256 + threadIdx.x; idx < SROWS * 1024; idx += 256 * 256) {
        int r = idx >> 10;
        int64_t off = (int64_t)(r * SSTRIDE) * 1024 + (idx & 1023);
        float ax = b0, ay = b0, az = b0, aw = b0;
#pragma unroll
        for (int c = 0; c < NC; ++c) {
            float4 t = a4[(int64_t)c * TOTAL4 + off];
            ax += wr[c] * t.x; ay += wr[c] * t.y; az += wr[c] * t.z; aw += wr[c] * t.w;
        }
        atomicAdd(&h[f2key(ax) >> 20], 1u);
        atomicAdd(&h[f2key(ay) >> 20], 1u);
        atomicAdd(&h[f2key(az) >> 20], 1u);
        atomicAdd(&h[f2key(aw) >> 20], 1u);
    }
    __syncthreads();
    for (int i = threadIdx.x; i < 4096; i += 256) {
        uint32_t c = h[i];
        if (c) atomicAdd(&meta[M_SHIST + i], c);
    }
}

// S2) bracket: blo = bin of sample rank LO, bhi = bin of sample rank HI
__global__ __launch_bounds__(256) void bracket_kernel(uint32_t* __restrict__ meta) {
    __shared__ uint32_t hl[4096];
    __shared__ uint32_t sc[256];
    __shared__ uint32_t res[2];
    select_bin(meta + M_SHIST, 4096, LO_RANK, hl, sc, res);
    if (threadIdx.x == 0) meta[M_BLO] = res[0];
    __syncthreads();
    select_bin(meta + M_SHIST, 4096, HI_RANK, hl, sc, res);
    if (threadIdx.x == 0) meta[M_BHI] = res[0];
}

// ---------------------------------------------------------------------------
// A) fused agg+mask+collect: NO agg store.   (R16, verified)
// ---------------------------------------------------------------------------
__global__ __launch_bounds__(256) void aggmask_kernel(const float* __restrict__ attn,
        const float* __restrict__ w, const float* __restrict__ bb,
        uint32_t* __restrict__ meta, uint32_t* __restrict__ M,
        float* __restrict__ candV, uint32_t* __restrict__ candC) {
    __shared__ uint32_t mrow[512];
    __shared__ uint32_t candH[256];
    __shared__ uint32_t cnt, nbel;
    int t = threadIdx.x;
    for (int i = t; i < 256; i += 256) candH[i] = 0;
    if (t == 0) { cnt = 0; nbel = 0; }
    float wr[NC];
#pragma unroll
    for (int c = 0; c < NC; ++c) wr[c] = w[c];
    float b0 = bb[0];
    uint32_t blo = meta[M_BLO], bhi = meta[M_BHI];
    __syncthreads();
    const float4* a4 = (const float4*)attn;
    float*    regV = candV + (size_t)blockIdx.x * CHUNK_V;
    uint32_t* regC = candC + (size_t)blockIdx.x * CHUNK_V;
    int64_t base = (int64_t)blockIdx.x * 4096;
    int u0 = blockIdx.x * 4;
    uint32_t below_t = 0;
    for (int it = 0; it < 16; ++it) {
        int li = it * 256 + t;
        float ax = b0, ay = b0, az = b0, aw = b0;
#pragma unroll
        for (int c = 0; c < NC; ++c) {
            float4 v = a4[(int64_t)c * TOTAL4 + base + li];
            ax += wr[c] * v.x; ay += wr[c] * v.y; az += wr[c] * v.z; aw += wr[c] * v.w;
        }
        int u = u0 + (li >> 10);
        int vcol = (li & 1023) * 4;
        float vals[4] = {ax, ay, az, aw};
        uint32_t nib = 0;
#pragma unroll
        for (int j = 0; j < 4; ++j) {
            float val = vals[j];
            uint32_t k = f2key(val);
            uint32_t top = k >> 20;
            if ((top > bhi) || (u == vcol + j)) nib |= (1u << j);
            if (top < blo) ++below_t;
            else if (top <= bhi) {
                uint32_t p = atomicAdd(&cnt, 1u);
                regV[p] = val;
                regC[p] = ((uint32_t)u << 12) | (uint32_t)(vcol + j);
                atomicAdd(&candH[min(top - blo, 255u)], 1u);
            }
        }
        uint32_t wd = nib << ((t & 7) * 4);
        wd |= (uint32_t)__shfl_xor((int)wd, 1);
        wd |= (uint32_t)__shfl_xor((int)wd, 2);
        wd |= (uint32_t)__shfl_xor((int)wd, 4);
        if ((t & 7) == 0) mrow[li >> 3] = wd;
    }
    atomicAdd(&nbel, below_t);
    __syncthreads();
    uint32_t* Mdst = M + (size_t)blockIdx.x * 512;
    Mdst[t] = mrow[t];
    Mdst[t + 256] = mrow[t + 256];
    uint32_t c = candH[t];
    if (c) atomicAdd(&meta[M_CH1 + t], c);
    if (t == 0) {
        meta[M_CNTS + blockIdx.x] = cnt;
        if (nbel) atomicAdd(&meta[M_NBEL], nbel);
    }
}

// ---------------------------------------------------------------------------
// C2) select level-1 over candHist1 (target r = K0 - nBelow); hist mid-12 bits
// ---------------------------------------------------------------------------
__global__ __launch_bounds__(256) void cand1_kernel(const float* __restrict__ candV,
        uint32_t* __restrict__ meta) {
    __shared__ uint32_t hl[4096];
    __shared__ uint32_t sc[256];
    __shared__ uint32_t res[2];
    int t = threadIdx.x;
    uint32_t r = K0_RANK - meta[M_NBEL];
    uint32_t blo = meta[M_BLO];
    select_bin(meta + M_CH1, 256, r, hl, sc, res);
    uint32_t b1c = blo + res[0];
    uint32_t r1 = res[1];
    if (t == 0) { meta[M_SELX + 0] = b1c; meta[M_SELX + 1] = r1; }
    for (int i = t; i < 4096; i += 256) hl[i] = 0;
    __syncthreads();
    uint32_t n = meta[M_CNTS + blockIdx.x];
    const float* region = candV + (size_t)blockIdx.x * CHUNK_V;
    for (uint32_t i = t; i < n; i += 256) {
        uint32_t key = f2key(region[i]);
        if ((key >> 20) == b1c) atomicAdd(&hl[(key >> 8) & 0xFFFu], 1u);
    }
    __syncthreads();
    for (int i = t; i < 4096; i += 256) {
        uint32_t c = hl[i];
        if (c) atomicAdd(&meta[M_CH2 + i], c);
    }
}

// ---------------------------------------------------------------------------
// C3) select level-2 over candHist2; hist low-8 within prefix24 + min above
// ---------------------------------------------------------------------------
__global__ __launch_bounds__(256) void cand2_kernel(const float* __restrict__ candV,
        uint32_t* __restrict__ meta) {
    __shared__ uint32_t hl[4096];
    __shared__ uint32_t sc[256];
    __shared__ uint32_t res[2];
    __shared__ uint32_t hB[256];
    __shared__ uint32_t ms;
    int t = threadIdx.x;
    uint32_t r1 = meta[M_SELX + 1];
    uint32_t b1c = meta[M_SELX + 0];
    select_bin(meta + M_CH2, 4096, r1, hl, sc, res);
    uint32_t p24 = (b1c << 12) | res[0];
    hB[t] = 0;
    if (t == 0) {
        ms = 0xFFFFFFFFu;
        meta[M_SELX + 2] = res[0]; meta[M_SELX + 3] = res[1];
    }
    uint32_t n = meta[M_CNTS + blockIdx.x];
    const float* region = candV + (size_t)blockIdx.x * CHUNK_V;
    __syncthreads();
    uint32_t mn = 0xFFFFFFFFu;
    for (uint32_t i = t; i < n; i += 256) {
        uint32_t key = f2key(region[i]);
        uint32_t hi = key >> 8;
        if (hi == p24) atomicAdd(&hB[key & 0xFFu], 1u);
        else if (hi > p24) mn = min(mn, key);
    }
    atomicMin(&ms, mn);
    __syncthreads();
    uint32_t c = hB[t];
    if (c) atomicAdd(&meta[M_HB + t], c);
    if (t == 0 && ms != 0xFFFFFFFFu) atomicMax(&meta[M_MXM], ~ms);
}

// ---------------------------------------------------------------------------
// C4) walk histB -> key0, thresh; patch candidates >= thresh into M
// ---------------------------------------------------------------------------
__global__ __launch_bounds__(256) void candfix_kernel(const float* __restrict__ candV,
        const uint32_t* __restrict__ candC, uint32_t* __restrict__ meta,
        uint32_t* __restrict__ M) {
    __shared__ uint32_t h[256];
    __shared__ float thr;
    int t = threadIdx.x;
    h[t] = meta[M_HB + t];
    __syncthreads();
    if (t == 0) {
        uint32_t b1c = meta[M_SELX + 0], b2c = meta[M_SELX + 2], r2 = meta[M_SELX + 3];
        uint32_t cum = 0; int b = 0;
        while (b < 255 && cum + h[b] <= r2) { cum += h[b]; ++b; }
        uint32_t key0 = (b1c << 20) | (b2c << 8) | (uint32_t)b;
        uint32_t cle = cum + h[b];
        uint32_t key1;
        if (cle >= r2 + 2u) key1 = key0;
        else {
            int nb = b + 1;
            while (nb < 256 && h[nb] == 0) ++nb;
            key1 = (nb < 256) ? ((b1c << 20) | (b2c << 8) | (uint32_t)nb) : ~meta[M_MXM];
        }
        float v0 = key2f(key0);
        float v1 = key2f(key1);
        thr = v0 + 0.5f * (v1 - v0);   // same formula as R1-R16 (verified)
        meta[M_SELX + 4] = __float_as_uint(thr);
    }
    __syncthreads();
    float th = thr;
    uint32_t n = meta[M_CNTS + blockIdx.x];
    const float*    regV = candV + (size_t)blockIdx.x * CHUNK_V;
    const uint32_t* regC = candC + (size_t)blockIdx.x * CHUNK_V;
    for (uint32_t i = t; i < n; i += 256) {
        if (regV[i] >= th) {
            uint32_t c = regC[i];
            uint32_t u = c >> 12, v = c & 0xFFFu;
            atomicOr(&M[(size_t)u * 128 + (v >> 5)], 1u << (v & 31u));
        }
    }
}

// ---------------------------------------------------------------------------
// T) transpose M[u][v] -> B[v][u], deg[v]   (R16, verified)
// ---------------------------------------------------------------------------
__global__ __launch_bounds__(256) void transposeB_kernel(const uint32_t* __restrict__ M,
        uint32_t* __restrict__ B, uint32_t* __restrict__ deg) {
    __shared__ uint32_t tile[4][64][2];
    int wave = threadIdx.x >> 6, lane = threadIdx.x & 63;
    int tileId = blockIdx.x * 4 + wave;
    int u0 = (tileId & 63) * 64;
    int v0 = (tileId >> 6) * 64;
    uint2 two = *(const uint2*)(M + (size_t)(u0 + lane) * 128 + (v0 >> 5));
    tile[wave][lane][0] = two.x;
    tile[wave][lane][1] = two.y;
    __syncthreads();
    int sh = lane & 31, hw = lane >> 5;
    uint32_t w0 = 0, w1 = 0;
#pragma unroll
    for (int i = 0; i < 32; ++i) {
        w0 |= ((tile[wave][i][hw] >> sh) & 1u) << i;
        w1 |= ((tile[wave][32 + i][hw] >> sh) & 1u) << i;
    }
    B[(size_t)(v0 + lane) * 128 + (u0 >> 5)]     = w0;
    B[(size_t)(v0 + lane) * 128 + (u0 >> 5) + 1] = w1;
    uint32_t d = __popc(w0) + __popc(w1);
    if (d) atomicAdd(&deg[v0 + lane], d);
}

// ---------------------------------------------------------------------------
// spmmX: t[v] = s_v * sum_u A[u,v] * s_u * x_h[u]   (256B fp16 row gathers)
// ---------------------------------------------------------------------------
static __device__ __forceinline__ uint32_t build_idx(const uint32_t* __restrict__ B,
                                                     int v, int t, uint16_t* idx) {
    const uint32_t* row = B + (int64_t)v * 128;
    uint32_t w0 = row[t], w1 = row[t + 64];
    uint32_t pc0 = __popc(w0), pc1 = __popc(w1);
    int s0 = (int)pc0, s1 = (int)pc1;
#pragma unroll
    for (int d = 1; d < 64; d <<= 1) {
        int a = __shfl_up(s0, d);
        int b = __shfl_up(s1, d);
        if (t >= d) { s0 += a; s1 += b; }
    }
    uint32_t tot0 = (uint32_t)__shfl(s0, 63);
    uint32_t cnt  = tot0 + (uint32_t)__shfl(s1, 63);
    uint32_t p = (uint32_t)s0 - pc0;
    uint32_t m = w0;
    int ub = t * 32;
    while (m) { int bi = __ffs(m) - 1; m &= m - 1; idx[p++] = (uint16_t)(ub + bi); }
    p = tot0 + (uint32_t)s1 - pc1;
    m = w1;
    ub = (t + 64) * 32;
    while (m) { int bi = __ffs(m) - 1; m &= m - 1; idx[p++] = (uint16_t)(ub + bi); }
    __syncthreads();
    return cnt;
}

__global__ __launch_bounds__(64) void spmmX_kernel(const uint32_t* __restrict__ B,
        const _Float16* __restrict__ x_h, const uint32_t* __restrict__ deg,
        float* __restrict__ t_out) {
    __shared__ uint16_t idx[4096];
    int v = blockIdx.x;
    int t = threadIdx.x;
    uint32_t cnt = build_idx(B, v, t, idx);
    const half2v* xp = (const half2v*)x_h;    // row = 64 half2
    float ax = 0.f, ay = 0.f;
    uint32_t i = 0;
    for (; i + 8 <= cnt; i += 8) {
#pragma unroll
        for (int q = 0; q < 8; ++q) {
            int u = idx[i + q];
            float su = rsqrtf((float)deg[u]);
            half2v a = xp[u * 64 + t];
            ax += su * (float)a[0]; ay += su * (float)a[1];
        }
    }
    for (; i < cnt; ++i) {
        int u = idx[i];
        float su = rsqrtf((float)deg[u]);
        half2v a = xp[u * 64 + t];
        ax += su * (float)a[0]; ay += su * (float)a[1];
    }
    float sv = rsqrtf((float)deg[v]);
    float2 r; r.x = sv * ax; r.y = sv * ay;
    ((float2*)t_out)[(int64_t)v * 64 + t] = r;
}

// ---------------------------------------------------------------------------
// fused MLP: h1 = relu(t@W1 + b1) (LDS); g2 = s_u * (h1@W2) -> fp16
// ---------------------------------------------------------------------------
__global__ __launch_bounds__(256) void mlp_kernel(const float* __restrict__ t_in,
        const float* __restrict__ W1, const float* __restrict__ b1,
        const float* __restrict__ W2, const uint32_t* __restrict__ deg,
        _Float16* __restrict__ g2) {
    __shared__ float tr[8 * 128];
    __shared__ float h1s[8 * 256];
    __shared__ float sr[8];
    int u0 = blockIdx.x * 8;
    int t = threadIdx.x;
    ((float4*)tr)[t] = ((const float4*)(t_in + (int64_t)u0 * 128))[t];
    if (t < 8) sr[t] = rsqrtf((float)deg[u0 + t]);
    __syncthreads();
    // phase 1: h1 rows (ch = t)
    {
        float acc[8] = {0, 0, 0, 0, 0, 0, 0, 0};
        for (int k = 0; k < 128; k += 4) {
            float w0 = W1[(k + 0) * 256 + t], w1 = W1[(k + 1) * 256 + t];
            float w2 = W1[(k + 2) * 256 + t], w3 = W1[(k + 3) * 256 + t];
#pragma unroll
            for (int r = 0; r < 8; ++r) {
                float4 tv = *(const float4*)&tr[r * 128 + k];
                acc[r] += tv.x * w0 + tv.y * w1 + tv.z * w2 + tv.w * w3;
            }
        }
        float bb = b1[t];
#pragma unroll
        for (int r = 0; r < 8; ++r)
            h1s[r * 256 + t] = fmaxf(acc[r] + bb, 0.f);
    }
    __syncthreads();
    // phase 2: g2 rows (col = t&127, 4 rows per half-block)
    {
        int col = t & 127;
        int roff = (t >> 7) * 4;
        float acc[4] = {0, 0, 0, 0};
        for (int k = 0; k < 256; k += 4) {
            float w0 = W2[(k + 0) * 128 + col], w1 = W2[(k + 1) * 128 + col];
            float w2 = W2[(k + 2) * 128 + col], w3 = W2[(k + 3) * 128 + col];
#pragma unroll
            for (int r = 0; r < 4; ++r) {
                float4 hv = *(const float4*)&h1s[(roff + r) * 256 + k];
                acc[r] += hv.x * w0 + hv.y * w1 + hv.z * w2 + hv.w * w3;
            }
        }
#pragma unroll
        for (int r = 0; r < 4; ++r)
            g2[(int64_t)(u0 + roff + r) * 128 + col] = (_Float16)(sr[roff + r] * acc[r]);
    }
}

// ---------------------------------------------------------------------------
// spmm2: out[v] = s_v * sum A[u,v] g2[u] + b2   (R16, verified)
// ---------------------------------------------------------------------------
__global__ __launch_bounds__(64) void spmm2_kernel(const uint32_t* __restrict__ B,
        const _Float16* __restrict__ g2, const uint32_t* __restrict__ deg,
        const float* __restrict__ b2, float* __restrict__ out) {
    __shared__ uint16_t idx[4096];
    int v = blockIdx.x;
    int t = threadIdx.x;
    uint32_t cnt = build_idx(B, v, t, idx);
    const half2v* gp = (const half2v*)g2;
    float ax = 0.f, ay = 0.f;
    uint32_t i = 0;
    for (; i + 8 <= cnt; i += 8) {
#pragma unroll
        for (int q = 0; q < 8; ++q) {
            half2v a = gp[idx[i + q] * 64 + t];
            ax += (float)a[0]; ay += (float)a[1];
        }
    }
    for (; i < cnt; ++i) {
        half2v a = gp[idx[i] * 64 + t];
        ax += (float)a[0]; ay += (float)a[1];
    }
    float sv = rsqrtf((float)deg[v]);
    float2 bb = ((const float2*)b2)[t];
    float2 r;
    r.x = sv * ax + bb.x;
    r.y = sv * ay + bb.y;
    ((float2*)out)[(int64_t)v * 64 + t] = r;
}

// ---------------------------------------------------------------------------
extern "C" void kernel_launch(void* const* d_in, const int* in_sizes, int n_in,
                              void* d_out, int out_size, void* d_ws, size_t ws_size,
                              hipStream_t stream) {
    const float* x    = (const float*)d_in[0];
    const float* attn = (const float*)d_in[1];
    const float* aggw = (const float*)d_in[2];
    const float* aggb = (const float*)d_in[3];
    const float* W1   = (const float*)d_in[4];
    const float* b1   = (const float*)d_in[5];
    const float* W2   = (const float*)d_in[6];
    const float* b2   = (const float*)d_in[7];
    float* out = (float*)d_out;

    char* ws = (char*)d_ws;
    size_t OFF_META  = 0;                                           // 56 KB
    size_t OFF_M     = OFF_META + 65536;                            // 2 MB rowmask
    size_t OFF_B     = OFF_M + (size_t)N_NODES * 128 * 4;           // 2 MB
    size_t OFF_CV    = OFF_B + (size_t)N_NODES * 128 * 4;           // 64 MB
    size_t OFF_CC    = OFF_CV + (size_t)1024 * CHUNK_V * 4;         // 64 MB
    size_t OFF_XH    = OFF_CC + (size_t)1024 * CHUNK_V * 4;         // 1 MB fp16 x
    size_t OFF_T     = OFF_XH + (size_t)N_NODES * 128 * 2;          // 2 MB fp32 t
    size_t OFF_G2    = OFF_T + (size_t)N_NODES * 128 * 4;           // 1 MB fp16 g2

    uint32_t* meta  = (uint32_t*)(ws + OFF_META);
    uint32_t* Mm    = (uint32_t*)(ws + OFF_M);
    uint32_t* Bm    = (uint32_t*)(ws + OFF_B);
    float*    candV = (float*)(ws + OFF_CV);
    uint32_t* candC = (uint32_t*)(ws + OFF_CC);
    _Float16* x_h   = (_Float16*)(ws + OFF_XH);
    float*    t_ws  = (float*)(ws + OFF_T);
    _Float16* g2    = (_Float16*)(ws + OFF_G2);
    uint32_t* deg   = meta + M_DEG;

    // race-free META zeroing: stream-ordered, completes before sample_kernel
    hipMemsetAsync(meta, 0, (size_t)M_WORDS * 4, stream);

    sample_kernel<<<256, 256, 0, stream>>>(attn, aggw, aggb, meta, x, x_h);
    bracket_kernel<<<1, 256, 0, stream>>>(meta);
    aggmask_kernel<<<1024, 256, 0, stream>>>(attn, aggw, aggb, meta, Mm, candV, candC);
    cand1_kernel<<<1024, 256, 0, stream>>>(candV, meta);
    cand2_kernel<<<1024, 256, 0, stream>>>(candV, meta);
    candfix_kernel<<<1024, 256, 0, stream>>>(candV, candC, meta, Mm);
    transposeB_kernel<<<1024, 256, 0, stream>>>(Mm, Bm, deg);

    spmmX_kernel<<<N_NODES, 64, 0, stream>>>(Bm, x_h, deg, t_ws);
    mlp_kernel<<<512, 256, 0, stream>>>(t_ws, W1, b1, W2, deg, g2);
    spmm2_kernel<<<N_NODES, 64, 0, stream>>>(Bm, g2, deg, b2, out);
}

// Round 18
// 315.783 us; speedup vs baseline: 1.1973x; 1.1094x over previous
//
#include <hip/hip_runtime.h>
#include <stdint.h>

#define N_NODES 4096
#define NNN ((int64_t)N_NODES * (int64_t)N_NODES)
#define TOTAL4 (NNN / 4)
#define NC 12
// floor(0.9 * (N*N - 1)) = 15099493 (frac = 0.5)
#define K0_RANK 15099493u

// sample: rows u = 25*r, r in [0,164) -> N_s = 164*4096 = 671744
#define SROWS 164
#define SSTRIDE 25
#define LO_RANK 601210u   // floor(0.895 * NSAMP)
#define HI_RANK 607929u   // ceil (0.905 * NSAMP)

// META layout (u32 words)
#define M_SHIST 0        // 4096  sample hist (key>>20)
#define M_CH1   4096     // 256   candidate top-bin hist (rel blo, clamped)
#define M_CH2   4352     // 4096  candidate mid-12 hist within b1c
#define M_HB    8448     // 256   candidate low-8 hist within prefix24
#define M_DEG   8704     // 4096
#define M_CNTS  12800    // 1024  per-block candidate counts
#define M_BLO   13824
#define M_BHI   13825
#define M_NBEL  13826
#define M_MXM   13827    // atomicMax of ~key over cand keys with (key>>8) > prefix24
#define M_SELX  13828    // [0]=b1c [1]=r1 [2]=b2c [3]=r2 [4]=thresh bits
#define M_WORDS 14336

#define CHUNK_V 16384

typedef __attribute__((ext_vector_type(2))) _Float16 half2v;
typedef __attribute__((ext_vector_type(4))) float f4v;

static __device__ __forceinline__ uint32_t f2key(float f) {
    uint32_t x = __float_as_uint(f);
    return (x & 0x80000000u) ? ~x : (x | 0x80000000u);
}
static __device__ __forceinline__ float key2f(uint32_t k) {
    uint32_t x = (k & 0x80000000u) ? (k & 0x7FFFFFFFu) : ~k;
    return __uint_as_float(x);
}

// 256-thread block-wide select over nb-bin hist -> out[0]=bin, out[1]=residual rank
static __device__ __forceinline__ void select_bin(const uint32_t* __restrict__ gh,
        int nb, uint32_t target, uint32_t* hl, uint32_t* sc, uint32_t* out) {
    int t = threadIdx.x;
    int per = nb >> 8;
    for (int i = t; i < nb; i += 256) hl[i] = gh[i];
    __syncthreads();
    uint32_t p = 0;
    for (int i = 0; i < per; ++i) p += hl[t * per + i];
    sc[t] = p;
    __syncthreads();
    for (int d = 1; d < 256; d <<= 1) {
        uint32_t v = (t >= d) ? sc[t - d] : 0u;
        __syncthreads();
        sc[t] += v;
        __syncthreads();
    }
    uint32_t excl = sc[t] - p;
    if (p > 0 && target >= excl && target < excl + p) {
        uint32_t cum = excl; int b = t * per;
        while (cum + hl[b] <= target) { cum += hl[b]; ++b; }
        out[0] = (uint32_t)b; out[1] = target - cum;
    }
    __syncthreads();
}

// ---------------------------------------------------------------------------
// S) sample 164 rows -> hist of key>>20; convert x -> fp16.
//    META zeroed by stream-ordered memset BEFORE this kernel (race-free).
// ---------------------------------------------------------------------------
__global__ __launch_bounds__(256) void sample_kernel(const float* __restrict__ attn,
        const float* __restrict__ w, const float* __restrict__ bb,
        uint32_t* __restrict__ meta, const float* __restrict__ x,
        _Float16* __restrict__ x_h) {
    // x -> fp16 (4096*128 = 524288 floats = 262144 float2)
    {
        const float2* x2 = (const float2*)x;
        half2v* xh2 = (half2v*)x_h;
        for (int i = blockIdx.x * 256 + threadIdx.x; i < 262144; i += 256 * 256) {
            float2 v = x2[i];
            half2v h; h[0] = (_Float16)v.x; h[1] = (_Float16)v.y;
            xh2[i] = h;
        }
    }
    __shared__ uint32_t h[4096];
    for (int i = threadIdx.x; i < 4096; i += 256) h[i] = 0;
    float wr[NC];
#pragma unroll
    for (int c = 0; c < NC; ++c) wr[c] = w[c];
    float b0 = bb[0];
    __syncthreads();
    const f4v* a4 = (const f4v*)attn;
    for (int idx = blockIdx.x * 256 + threadIdx.x; idx < SROWS * 1024; idx += 256 * 256) {
        int r = idx >> 10;
        int64_t off = (int64_t)(r * SSTRIDE) * 1024 + (idx & 1023);
        float ax = b0, ay = b0, az = b0, aw = b0;
#pragma unroll
        for (int c = 0; c < NC; ++c) {
            f4v t = __builtin_nontemporal_load(a4 + (int64_t)c * TOTAL4 + off);
            ax += wr[c] * t.x; ay += wr[c] * t.y; az += wr[c] * t.z; aw += wr[c] * t.w;
        }
        atomicAdd(&h[f2key(ax) >> 20], 1u);
        atomicAdd(&h[f2key(ay) >> 20], 1u);
        atomicAdd(&h[f2key(az) >> 20], 1u);
        atomicAdd(&h[f2key(aw) >> 20], 1u);
    }
    __syncthreads();
    for (int i = threadIdx.x; i < 4096; i += 256) {
        uint32_t c = h[i];
        if (c) atomicAdd(&meta[M_SHIST + i], c);
    }
}

// ---------------------------------------------------------------------------
// A) fused bracket+agg+mask+collect: NO agg store.  Each block recomputes the
//    bracket from SHIST (complete, stream-ordered) — no separate launch.
// ---------------------------------------------------------------------------
__global__ __launch_bounds__(256) void aggmask_kernel(const float* __restrict__ attn,
        const float* __restrict__ w, const float* __restrict__ bb,
        uint32_t* __restrict__ meta, uint32_t* __restrict__ M,
        float* __restrict__ candV, uint32_t* __restrict__ candC) {
    __shared__ uint32_t hl[4096];
    __shared__ uint32_t sc[256];
    __shared__ uint32_t res[2];
    __shared__ uint32_t mrow[512];
    __shared__ uint32_t candH[256];
    __shared__ uint32_t cnt, nbel;
    int t = threadIdx.x;
    // bracket inline (same math as verified bracket_kernel; all blocks identical)
    select_bin(meta + M_SHIST, 4096, LO_RANK, hl, sc, res);
    uint32_t blo = res[0];
    select_bin(meta + M_SHIST, 4096, HI_RANK, hl, sc, res);
    uint32_t bhi = res[0];
    for (int i = t; i < 256; i += 256) candH[i] = 0;
    if (t == 0) {
        meta[M_BLO] = blo; meta[M_BHI] = bhi;   // same value from every block
        cnt = 0; nbel = 0;
    }
    float wr[NC];
#pragma unroll
    for (int c = 0; c < NC; ++c) wr[c] = w[c];
    float b0 = bb[0];
    __syncthreads();
    const f4v* a4 = (const f4v*)attn;
    float*    regV = candV + (size_t)blockIdx.x * CHUNK_V;
    uint32_t* regC = candC + (size_t)blockIdx.x * CHUNK_V;
    int64_t base = (int64_t)blockIdx.x * 4096;
    int u0 = blockIdx.x * 4;
    uint32_t below_t = 0;
    for (int it = 0; it < 16; ++it) {
        int li = it * 256 + t;
        float ax = b0, ay = b0, az = b0, aw = b0;
#pragma unroll
        for (int c = 0; c < NC; ++c) {
            f4v v = __builtin_nontemporal_load(a4 + (int64_t)c * TOTAL4 + base + li);
            ax += wr[c] * v.x; ay += wr[c] * v.y; az += wr[c] * v.z; aw += wr[c] * v.w;
        }
        int u = u0 + (li >> 10);
        int vcol = (li & 1023) * 4;
        float vals[4] = {ax, ay, az, aw};
        uint32_t nib = 0;
#pragma unroll
        for (int j = 0; j < 4; ++j) {
            float val = vals[j];
            uint32_t k = f2key(val);
            uint32_t top = k >> 20;
            if ((top > bhi) || (u == vcol + j)) nib |= (1u << j);
            if (top < blo) ++below_t;
            else if (top <= bhi) {
                uint32_t p = atomicAdd(&cnt, 1u);
                regV[p] = val;
                regC[p] = ((uint32_t)u << 12) | (uint32_t)(vcol + j);
                atomicAdd(&candH[min(top - blo, 255u)], 1u);
            }
        }
        uint32_t wd = nib << ((t & 7) * 4);
        wd |= (uint32_t)__shfl_xor((int)wd, 1);
        wd |= (uint32_t)__shfl_xor((int)wd, 2);
        wd |= (uint32_t)__shfl_xor((int)wd, 4);
        if ((t & 7) == 0) mrow[li >> 3] = wd;
    }
    atomicAdd(&nbel, below_t);
    __syncthreads();
    uint32_t* Mdst = M + (size_t)blockIdx.x * 512;
    Mdst[t] = mrow[t];
    Mdst[t + 256] = mrow[t + 256];
    uint32_t c = candH[t];
    if (c) atomicAdd(&meta[M_CH1 + t], c);
    if (t == 0) {
        meta[M_CNTS + blockIdx.x] = cnt;
        if (nbel) atomicAdd(&meta[M_NBEL], nbel);
    }
}

// ---------------------------------------------------------------------------
// C2) select level-1 over candHist1 (target r = K0 - nBelow); hist mid-12 bits
// ---------------------------------------------------------------------------
__global__ __launch_bounds__(256) void cand1_kernel(const float* __restrict__ candV,
        uint32_t* __restrict__ meta) {
    __shared__ uint32_t hl[4096];
    __shared__ uint32_t sc[256];
    __shared__ uint32_t res[2];
    int t = threadIdx.x;
    uint32_t r = K0_RANK - meta[M_NBEL];
    uint32_t blo = meta[M_BLO];
    select_bin(meta + M_CH1, 256, r, hl, sc, res);
    uint32_t b1c = blo + res[0];
    uint32_t r1 = res[1];
    if (t == 0) { meta[M_SELX + 0] = b1c; meta[M_SELX + 1] = r1; }
    for (int i = t; i < 4096; i += 256) hl[i] = 0;
    __syncthreads();
    uint32_t n = meta[M_CNTS + blockIdx.x];
    const float* region = candV + (size_t)blockIdx.x * CHUNK_V;
    for (uint32_t i = t; i < n; i += 256) {
        uint32_t key = f2key(region[i]);
        if ((key >> 20) == b1c) atomicAdd(&hl[(key >> 8) & 0xFFFu], 1u);
    }
    __syncthreads();
    for (int i = t; i < 4096; i += 256) {
        uint32_t c = hl[i];
        if (c) atomicAdd(&meta[M_CH2 + i], c);
    }
}

// ---------------------------------------------------------------------------
// C3) select level-2 over candHist2; hist low-8 within prefix24 + min above
// ---------------------------------------------------------------------------
__global__ __launch_bounds__(256) void cand2_kernel(const float* __restrict__ candV,
        uint32_t* __restrict__ meta) {
    __shared__ uint32_t hl[4096];
    __shared__ uint32_t sc[256];
    __shared__ uint32_t res[2];
    __shared__ uint32_t hB[256];
    __shared__ uint32_t ms;
    int t = threadIdx.x;
    uint32_t r1 = meta[M_SELX + 1];
    uint32_t b1c = meta[M_SELX + 0];
    select_bin(meta + M_CH2, 4096, r1, hl, sc, res);
    uint32_t p24 = (b1c << 12) | res[0];
    hB[t] = 0;
    if (t == 0) {
        ms = 0xFFFFFFFFu;
        meta[M_SELX + 2] = res[0]; meta[M_SELX + 3] = res[1];
    }
    uint32_t n = meta[M_CNTS + blockIdx.x];
    const float* region = candV + (size_t)blockIdx.x * CHUNK_V;
    __syncthreads();
    uint32_t mn = 0xFFFFFFFFu;
    for (uint32_t i = t; i < n; i += 256) {
        uint32_t key = f2key(region[i]);
        uint32_t hi = key >> 8;
        if (hi == p24) atomicAdd(&hB[key & 0xFFu], 1u);
        else if (hi > p24) mn = min(mn, key);
    }
    atomicMin(&ms, mn);
    __syncthreads();
    uint32_t c = hB[t];
    if (c) atomicAdd(&meta[M_HB + t], c);
    if (t == 0 && ms != 0xFFFFFFFFu) atomicMax(&meta[M_MXM], ~ms);
}

// ---------------------------------------------------------------------------
// C4) walk histB -> key0, thresh; patch candidates >= thresh into M
// ---------------------------------------------------------------------------
__global__ __launch_bounds__(256) void candfix_kernel(const float* __restrict__ candV,
        const uint32_t* __restrict__ candC, uint32_t* __restrict__ meta,
        uint32_t* __restrict__ M) {
    __shared__ uint32_t h[256];
    __shared__ float thr;
    int t = threadIdx.x;
    h[t] = meta[M_HB + t];
    __syncthreads();
    if (t == 0) {
        uint32_t b1c = meta[M_SELX + 0], b2c = meta[M_SELX + 2], r2 = meta[M_SELX + 3];
        uint32_t cum = 0; int b = 0;
        while (b < 255 && cum + h[b] <= r2) { cum += h[b]; ++b; }
        uint32_t key0 = (b1c << 20) | (b2c << 8) | (uint32_t)b;
        uint32_t cle = cum + h[b];
        uint32_t key1;
        if (cle >= r2 + 2u) key1 = key0;
        else {
            int nb = b + 1;
            while (nb < 256 && h[nb] == 0) ++nb;
            key1 = (nb < 256) ? ((b1c << 20) | (b2c << 8) | (uint32_t)nb) : ~meta[M_MXM];
        }
        float v0 = key2f(key0);
        float v1 = key2f(key1);
        thr = v0 + 0.5f * (v1 - v0);   // same formula as R1-R17 (verified)
        meta[M_SELX + 4] = __float_as_uint(thr);
    }
    __syncthreads();
    float th = thr;
    uint32_t n = meta[M_CNTS + blockIdx.x];
    const float*    regV = candV + (size_t)blockIdx.x * CHUNK_V;
    const uint32_t* regC = candC + (size_t)blockIdx.x * CHUNK_V;
    for (uint32_t i = t; i < n; i += 256) {
        if (regV[i] >= th) {
            uint32_t c = regC[i];
            uint32_t u = c >> 12, v = c & 0xFFFu;
            atomicOr(&M[(size_t)u * 128 + (v >> 5)], 1u << (v & 31u));
        }
    }
}

// ---------------------------------------------------------------------------
// T) transpose M[u][v] -> B[v][u], deg[v]
// ---------------------------------------------------------------------------
__global__ __launch_bounds__(256) void transposeB_kernel(const uint32_t* __restrict__ M,
        uint32_t* __restrict__ B, uint32_t* __restrict__ deg) {
    __shared__ uint32_t tile[4][64][2];
    int wave = threadIdx.x >> 6, lane = threadIdx.x & 63;
    int tileId = blockIdx.x * 4 + wave;
    int u0 = (tileId & 63) * 64;
    int v0 = (tileId >> 6) * 64;
    uint2 two = *(const uint2*)(M + (size_t)(u0 + lane) * 128 + (v0 >> 5));
    tile[wave][lane][0] = two.x;
    tile[wave][lane][1] = two.y;
    __syncthreads();
    int sh = lane & 31, hw = lane >> 5;
    uint32_t w0 = 0, w1 = 0;
#pragma unroll
    for (int i = 0; i < 32; ++i) {
        w0 |= ((tile[wave][i][hw] >> sh) & 1u) << i;
        w1 |= ((tile[wave][32 + i][hw] >> sh) & 1u) << i;
    }
    B[(size_t)(v0 + lane) * 128 + (u0 >> 5)]     = w0;
    B[(size_t)(v0 + lane) * 128 + (u0 >> 5) + 1] = w1;
    uint32_t d = __popc(w0) + __popc(w1);
    if (d) atomicAdd(&deg[v0 + lane], d);
}

// ---------------------------------------------------------------------------
// spmmX: t[v] = s_v * sum_u A[u,v] * s_u * x_h[u]   (256B fp16 row gathers)
// ---------------------------------------------------------------------------
static __device__ __forceinline__ uint32_t build_idx(const uint32_t* __restrict__ B,
                                                     int v, int t, uint16_t* idx) {
    const uint32_t* row = B + (int64_t)v * 128;
    uint32_t w0 = row[t], w1 = row[t + 64];
    uint32_t pc0 = __popc(w0), pc1 = __popc(w1);
    int s0 = (int)pc0, s1 = (int)pc1;
#pragma unroll
    for (int d = 1; d < 64; d <<= 1) {
        int a = __shfl_up(s0, d);
        int b = __shfl_up(s1, d);
        if (t >= d) { s0 += a; s1 += b; }
    }
    uint32_t tot0 = (uint32_t)__shfl(s0, 63);
    uint32_t cnt  = tot0 + (uint32_t)__shfl(s1, 63);
    uint32_t p = (uint32_t)s0 - pc0;
    uint32_t m = w0;
    int ub = t * 32;
    while (m) { int bi = __ffs(m) - 1; m &= m - 1; idx[p++] = (uint16_t)(ub + bi); }
    p = tot0 + (uint32_t)s1 - pc1;
    m = w1;
    ub = (t + 64) * 32;
    while (m) { int bi = __ffs(m) - 1; m &= m - 1; idx[p++] = (uint16_t)(ub + bi); }
    __syncthreads();
    return cnt;
}

__global__ __launch_bounds__(64) void spmmX_kernel(const uint32_t* __restrict__ B,
        const _Float16* __restrict__ x_h, const uint32_t* __restrict__ deg,
        float* __restrict__ t_out) {
    __shared__ uint16_t idx[4096];
    int v = blockIdx.x;
    int t = threadIdx.x;
    uint32_t cnt = build_idx(B, v, t, idx);
    const half2v* xp = (const half2v*)x_h;    // row = 64 half2
    float ax = 0.f, ay = 0.f;
    uint32_t i = 0;
    for (; i + 8 <= cnt; i += 8) {
#pragma unroll
        for (int q = 0; q < 8; ++q) {
            int u = idx[i + q];
            float su = rsqrtf((float)deg[u]);
            half2v a = xp[u * 64 + t];
            ax += su * (float)a[0]; ay += su * (float)a[1];
        }
    }
    for (; i < cnt; ++i) {
        int u = idx[i];
        float su = rsqrtf((float)deg[u]);
        half2v a = xp[u * 64 + t];
        ax += su * (float)a[0]; ay += su * (float)a[1];
    }
    float sv = rsqrtf((float)deg[v]);
    float2 r; r.x = sv * ax; r.y = sv * ay;
    ((float2*)t_out)[(int64_t)v * 64 + t] = r;
}

// ---------------------------------------------------------------------------
// fused MLP: h1 = relu(t@W1 + b1) (LDS); g2 = s_u * (h1@W2) -> fp16
// ---------------------------------------------------------------------------
__global__ __launch_bounds__(256) void mlp_kernel(const float* __restrict__ t_in,
        const float* __restrict__ W1, const float* __restrict__ b1,
        const float* __restrict__ W2, const uint32_t* __restrict__ deg,
        _Float16* __restrict__ g2) {
    __shared__ float tr[8 * 128];
    __shared__ float h1s[8 * 256];
    __shared__ float sr[8];
    int u0 = blockIdx.x * 8;
    int t = threadIdx.x;
    ((float4*)tr)[t] = ((const float4*)(t_in + (int64_t)u0 * 128))[t];
    if (t < 8) sr[t] = rsqrtf((float)deg[u0 + t]);
    __syncthreads();
    // phase 1: h1 rows (ch = t)
    {
        float acc[8] = {0, 0, 0, 0, 0, 0, 0, 0};
        for (int k = 0; k < 128; k += 4) {
            float w0 = W1[(k + 0) * 256 + t], w1 = W1[(k + 1) * 256 + t];
            float w2 = W1[(k + 2) * 256 + t], w3 = W1[(k + 3) * 256 + t];
#pragma unroll
            for (int r = 0; r < 8; ++r) {
                float4 tv = *(const float4*)&tr[r * 128 + k];
                acc[r] += tv.x * w0 + tv.y * w1 + tv.z * w2 + tv.w * w3;
            }
        }
        float bb = b1[t];
#pragma unroll
        for (int r = 0; r < 8; ++r)
            h1s[r * 256 + t] = fmaxf(acc[r] + bb, 0.f);
    }
    __syncthreads();
    // phase 2: g2 rows (col = t&127, 4 rows per half-block)
    {
        int col = t & 127;
        int roff = (t >> 7) * 4;
        float acc[4] = {0, 0, 0, 0};
        for (int k = 0; k < 256; k += 4) {
            float w0 = W2[(k + 0) * 128 + col], w1 = W2[(k + 1) * 128 + col];
            float w2 = W2[(k + 2) * 128 + col], w3 = W2[(k + 3) * 128 + col];
#pragma unroll
            for (int r = 0; r < 4; ++r) {
                float4 hv = *(const float4*)&h1s[(roff + r) * 256 + k];
                acc[r] += hv.x * w0 + hv.y * w1 + hv.z * w2 + hv.w * w3;
            }
        }
#pragma unroll
        for (int r = 0; r < 4; ++r)
            g2[(int64_t)(u0 + roff + r) * 128 + col] = (_Float16)(sr[roff + r] * acc[r]);
    }
}

// ---------------------------------------------------------------------------
// spmm2: out[v] = s_v * sum A[u,v] g2[u] + b2
// ---------------------------------------------------------------------------
__global__ __launch_bounds__(64) void spmm2_kernel(const uint32_t* __restrict__ B,
        const _Float16* __restrict__ g2, const uint32_t* __restrict__ deg,
        const float* __restrict__ b2, float* __restrict__ out) {
    __shared__ uint16_t idx[4096];
    int v = blockIdx.x;
    int t = threadIdx.x;
    uint32_t cnt = build_idx(B, v, t, idx);
    const half2v* gp = (const half2v*)g2;
    float ax = 0.f, ay = 0.f;
    uint32_t i = 0;
    for (; i + 8 <= cnt; i += 8) {
#pragma unroll
        for (int q = 0; q < 8; ++q) {
            half2v a = gp[idx[i + q] * 64 + t];
            ax += (float)a[0]; ay += (float)a[1];
        }
    }
    for (; i < cnt; ++i) {
        half2v a = gp[idx[i] * 64 + t];
        ax += (float)a[0]; ay += (float)a[1];
    }
    float sv = rsqrtf((float)deg[v]);
    float2 bb = ((const float2*)b2)[t];
    float2 r;
    r.x = sv * ax + bb.x;
    r.y = sv * ay + bb.y;
    ((float2*)out)[(int64_t)v * 64 + t] = r;
}

// ---------------------------------------------------------------------------
extern "C" void kernel_launch(void* const* d_in, const int* in_sizes, int n_in,
                              void* d_out, int out_size, void* d_ws, size_t ws_size,
                              hipStream_t stream) {
    const float* x    = (const float*)d_in[0];
    const float* attn = (const float*)d_in[1];
    const float* aggw = (const float*)d_in[2];
    const float* aggb = (const float*)d_in[3];
    const float* W1   = (const float*)d_in[4];
    const float* b1   = (const float*)d_in[5];
    const float* W2   = (const float*)d_in[6];
    const float* b2   = (const float*)d_in[7];
    float* out = (float*)d_out;

    char* ws = (char*)d_ws;
    size_t OFF_META  = 0;                                           // 56 KB
    size_t OFF_M     = OFF_META + 65536;                            // 2 MB rowmask
    size_t OFF_B     = OFF_M + (size_t)N_NODES * 128 * 4;           // 2 MB
    size_t OFF_CV    = OFF_B + (size_t)N_NODES * 128 * 4;           // 64 MB
    size_t OFF_CC    = OFF_CV + (size_t)1024 * CHUNK_V * 4;         // 64 MB
    size_t OFF_XH    = OFF_CC + (size_t)1024 * CHUNK_V * 4;         // 1 MB fp16 x
    size_t OFF_T     = OFF_XH + (size_t)N_NODES * 128 * 2;          // 2 MB fp32 t
    size_t OFF_G2    = OFF_T + (size_t)N_NODES * 128 * 4;           // 1 MB fp16 g2

    uint32_t* meta  = (uint32_t*)(ws + OFF_META);
    uint32_t* Mm    = (uint32_t*)(ws + OFF_M);
    uint32_t* Bm    = (uint32_t*)(ws + OFF_B);
    float*    candV = (float*)(ws + OFF_CV);
    uint32_t* candC = (uint32_t*)(ws + OFF_CC);
    _Float16* x_h   = (_Float16*)(ws + OFF_XH);
    float*    t_ws  = (float*)(ws + OFF_T);
    _Float16* g2    = (_Float16*)(ws + OFF_G2);
    uint32_t* deg   = meta + M_DEG;

    // race-free META zeroing: stream-ordered, completes before sample_kernel
    hipMemsetAsync(meta, 0, (size_t)M_WORDS * 4, stream);

    sample_kernel<<<256, 256, 0, stream>>>(attn, aggw, aggb, meta, x, x_h);
    aggmask_kernel<<<1024, 256, 0, stream>>>(attn, aggw, aggb, meta, Mm, candV, candC);
    cand1_kernel<<<1024, 256, 0, stream>>>(candV, meta);
    cand2_kernel<<<1024, 256, 0, stream>>>(candV, meta);
    candfix_kernel<<<1024, 256, 0, stream>>>(candV, candC, meta, Mm);
    transposeB_kernel<<<1024, 256, 0, stream>>>(Mm, Bm, deg);

    spmmX_kernel<<<N_NODES, 64, 0, stream>>>(Bm, x_h, deg, t_ws);
    mlp_kernel<<<512, 256, 0, stream>>>(t_ws, W1, b1, W2, deg, g2);
    spmm2_kernel<<<N_NODES, 64, 0, stream>>>(Bm, g2, deg, b2, out);
}